// Round 4
// baseline (181.391 us; speedup 1.0000x reference)
//
#include <hip/hip_runtime.h>
#include <math.h>

#define BB 4
#define NN 8192
#define KNB 16
#define DD 128
#define SS 17            // K+1 (self + neighbors)
#define M_TOT (BB*NN)    // 32768
#define WPAD 136         // padded inner stride (elems) for LDS tiles

typedef __attribute__((ext_vector_type(8))) short          bf8;
typedef __attribute__((ext_vector_type(4))) float          f4;
typedef __attribute__((ext_vector_type(4))) unsigned short u16x4;

static __device__ __forceinline__ unsigned short f2bf(float f) {
    unsigned u = __builtin_bit_cast(unsigned, f);
    u += 0x7fffu + ((u >> 16) & 1u);        // round-to-nearest-even
    return (unsigned short)(u >> 16);
}
static __device__ __forceinline__ float bf2f(unsigned short h) {
    return __builtin_bit_cast(float, (unsigned)h << 16);
}

// ---------------------------------------------------------------------------
// Transpose+convert the six 128x128 fp32 weights to bf16 W^T[n][k].
// ---------------------------------------------------------------------------
__global__ __launch_bounds__(256) void cvt_wT(
    const float* __restrict__ Wq, const float* __restrict__ Wk,
    const float* __restrict__ Wv, const float* __restrict__ Wo,
    const float* __restrict__ W1, const float* __restrict__ W2,
    unsigned short* __restrict__ out)
{
    int m = blockIdx.x >> 4;
    const float* src = (m == 0) ? Wq : (m == 1) ? Wk : (m == 2) ? Wv
                     : (m == 3) ? Wo : (m == 4) ? W1 : W2;
    unsigned short* dst = out + m * 16384;
    int o = (blockIdx.x & 15) * 1024 + threadIdx.x * 4;   // output idx [n][k]
    int n = o >> 7, k = o & 127;
    u16x4 r;
    #pragma unroll
    for (int i = 0; i < 4; ++i) r[i] = f2bf(src[(size_t)(k + i) * 128 + n]);
    *(u16x4*)(dst + o) = r;
}

// ---------------------------------------------------------------------------
// Fused fp32->bf16 convert + QKV projection.
// 64 rows/block, 4 waves. X staged once (fp32 read, bf16 in LDS), A-frags
// persist in registers across the three GEMMs; one 34.8 KB W buffer is
// re-staged per GEMM. Fragment maps (m89-verified): A[m=lane&15][k=quad*8+j],
// B[k=quad*8+j][n=lane&15], D[row=quad*4+r][col=lane&15].
// LDS 17.4 + 34.8 = 52.2 KB -> 3 blocks/CU.
// ---------------------------------------------------------------------------
__global__ __launch_bounds__(256) void qkv_kernel(
    const float* __restrict__ X, const unsigned short* __restrict__ WtT,
    const float* __restrict__ bq, const float* __restrict__ bk,
    const float* __restrict__ bv,
    unsigned short* __restrict__ qh, unsigned short* __restrict__ kh,
    unsigned short* __restrict__ vh)
{
    __shared__ unsigned short Xs[64 * WPAD];    // 17408 B
    __shared__ unsigned short Wb[128 * WPAD];   // 34816 B

    const int tid  = threadIdx.x;
    const int row0 = blockIdx.x * 64;

    // Stage X tile fp32 -> bf16 (coalesced float4 reads)
    {
        const float4* Xg = (const float4*)(X + (size_t)row0 * DD);
        #pragma unroll
        for (int i = 0; i < 8; ++i) {
            int idx = tid + i * 256;            // 0..2047
            int r = idx >> 5, c4 = idx & 31;
            float4 v = Xg[idx];
            u16x4 u;
            u[0] = f2bf(v.x); u[1] = f2bf(v.y); u[2] = f2bf(v.z); u[3] = f2bf(v.w);
            *(u16x4*)(Xs + r * WPAD + c4 * 4) = u;
        }
    }
    // Stage Wq^T
    #pragma unroll
    for (int i = 0; i < 8; ++i) {
        int c = tid + i * 256;
        int n = c >> 4, k8 = c & 15;
        *(bf8*)(Wb + n * WPAD + k8 * 8) = ((const bf8*)WtT)[c];
    }

    const int lane = tid & 63, wv = tid >> 6;
    const int wm = wv >> 1, wn = wv & 1;
    const int ln = lane & 15, quad = lane >> 4;
    __syncthreads();

    // A-frags: persistent across the 3 GEMMs (2 m-tiles x 4 k-steps)
    bf8 afr[2][4];
    #pragma unroll
    for (int mt = 0; mt < 2; ++mt)
        #pragma unroll
        for (int s = 0; s < 4; ++s)
            afr[mt][s] = *(const bf8*)(Xs + (wm * 32 + mt * 16 + ln) * WPAD + s * 32 + quad * 8);

    const float* biases[3] = { bq, bk, bv };
    unsigned short* outs[3] = { qh, kh, vh };

    #pragma unroll
    for (int g = 0; g < 3; ++g) {
        // B-frags for this GEMM
        bf8 bfr[4][4];
        #pragma unroll
        for (int t = 0; t < 4; ++t)
            #pragma unroll
            for (int s = 0; s < 4; ++s)
                bfr[t][s] = *(const bf8*)(Wb + (wn * 64 + t * 16 + ln) * WPAD + s * 32 + quad * 8);
        __syncthreads();   // B-frag reads done -> Wb free

        if (g < 2) {       // stage next W while doing MFMA
            const bf8* Wn = (const bf8*)(WtT + (g + 1) * 16384);
            #pragma unroll
            for (int i = 0; i < 8; ++i) {
                int c = tid + i * 256;
                int n = c >> 4, k8 = c & 15;
                *(bf8*)(Wb + n * WPAD + k8 * 8) = Wn[c];
            }
        }

        f4 acc[2][4] = {};
        #pragma unroll
        for (int s = 0; s < 4; ++s)
            #pragma unroll
            for (int t = 0; t < 4; ++t) {
                acc[0][t] = __builtin_amdgcn_mfma_f32_16x16x32_bf16(afr[0][s], bfr[t][s], acc[0][t], 0, 0, 0);
                acc[1][t] = __builtin_amdgcn_mfma_f32_16x16x32_bf16(afr[1][s], bfr[t][s], acc[1][t], 0, 0, 0);
            }

        const float* bias = biases[g];
        unsigned short* Y = outs[g];
        #pragma unroll
        for (int mt = 0; mt < 2; ++mt)
            #pragma unroll
            for (int t = 0; t < 4; ++t) {
                int col = wn * 64 + t * 16 + ln;
                float bc = bias[col];
                #pragma unroll
                for (int r = 0; r < 4; ++r) {
                    int row = row0 + wm * 32 + mt * 16 + quad * 4 + r;
                    Y[(size_t)row * DD + col] = f2bf(acc[mt][t][r] + bc);
                }
            }
        __syncthreads();   // Wb(g+1) staged & visible; loop
    }
}

// ---------------------------------------------------------------------------
// Fused attention + Wo + FFN(W1,relu,W2). 64 vertices/block, 4 waves.
// Attention: 8 lane-groups x 8 vertices, register-resident, ctx -> LDS tile.
// Then three chained MFMA GEMMs with the W buffer re-staged per GEMM; the
// ctx tile doubles as the intermediate activation tile. Final out fp32.
// LDS 17.4 + 34.8 = 52.2 KB -> 3 blocks/CU.
// ---------------------------------------------------------------------------
__global__ __launch_bounds__(256) void attn_ffn_kernel(
    const unsigned short* __restrict__ Qh, const unsigned short* __restrict__ Kh,
    const unsigned short* __restrict__ Vh, const int* __restrict__ nbr,
    const int* __restrict__ vlen, const unsigned short* __restrict__ WtT3,
    const float* __restrict__ bo, const float* __restrict__ b1,
    const float* __restrict__ b2, float* __restrict__ Out)
{
    __shared__ unsigned short Ct[64 * WPAD];    // ctx / out1 / h tile
    __shared__ unsigned short Wb[128 * WPAD];

    const int tid  = threadIdx.x;
    const int row0 = blockIdx.x * 64;

    // Stage Wo^T (not used by attention phase)
    #pragma unroll
    for (int i = 0; i < 8; ++i) {
        int c = tid + i * 256;
        int n = c >> 4, k8 = c & 15;
        *(bf8*)(Wb + n * WPAD + k8 * 8) = ((const bf8*)WtT3)[c];
    }

    // ---- attention phase ----
    {
        const int grp = tid >> 5;     // 0..7
        const int c   = tid & 31;     // 4-dim slot
        #pragma unroll 1
        for (int it = 0; it < 8; ++it) {
            const int vl = grp * 8 + it;
            const int v  = row0 + vl;
            const int b  = v >> 13;

            u16x4 qu = ((const u16x4*)Qh)[(size_t)v * 32 + c];
            const float q0 = bf2f(qu[0]), q1 = bf2f(qu[1]),
                        q2 = bf2f(qu[2]), q3 = bf2f(qu[3]);

            int rows[SS];
            rows[0] = v;
            #pragma unroll
            for (int s = 1; s < SS; ++s)
                rows[s] = b * NN + nbr[(size_t)v * KNB + (s - 1)];

            float sc[SS];
            #pragma unroll
            for (int s = 0; s < SS; ++s) {
                u16x4 ku = ((const u16x4*)Kh)[(size_t)rows[s] * 32 + c];
                float p = q0 * bf2f(ku[0]) + q1 * bf2f(ku[1])
                        + q2 * bf2f(ku[2]) + q3 * bf2f(ku[3]);
                p += __shfl_xor(p, 1, 8);
                p += __shfl_xor(p, 2, 8);
                p += __shfl_xor(p, 4, 8);
                sc[s] = p * 0.17677669529663687f;   // 1/sqrt(32)
            }

            const int len = vlen[v];
            float m = sc[0];
            #pragma unroll
            for (int s = 1; s < SS; ++s) m = (s <= len) ? fmaxf(m, sc[s]) : m;
            float sum = 0.f;
            #pragma unroll
            for (int s = 0; s < SS; ++s) {
                float e = (s <= len) ? __expf(sc[s] - m) : 0.f;
                sc[s] = e;
                sum += e;
            }
            const float inv = 1.f / sum;

            float a0 = 0.f, a1 = 0.f, a2 = 0.f, a3 = 0.f;
            #pragma unroll
            for (int s = 0; s < SS; ++s) {
                u16x4 vu = ((const u16x4*)Vh)[(size_t)rows[s] * 32 + c];
                float w = sc[s] * inv;
                a0 = fmaf(w, bf2f(vu[0]), a0);
                a1 = fmaf(w, bf2f(vu[1]), a1);
                a2 = fmaf(w, bf2f(vu[2]), a2);
                a3 = fmaf(w, bf2f(vu[3]), a3);
            }
            u16x4 r;
            r[0] = f2bf(a0); r[1] = f2bf(a1); r[2] = f2bf(a2); r[3] = f2bf(a3);
            *(u16x4*)(Ct + vl * WPAD + c * 4) = r;
        }
    }
    __syncthreads();   // ctx tile + Wo^T ready

    const int lane = tid & 63, wvv = tid >> 6;
    const int wm = wvv >> 1, wn = wvv & 1;
    const int ln = lane & 15, quad = lane >> 4;

    const float* biases[3] = { bo, b1, b2 };

    #pragma unroll
    for (int g = 0; g < 3; ++g) {
        bf8 afr[2][4], bfr[4][4];
        #pragma unroll
        for (int mt = 0; mt < 2; ++mt)
            #pragma unroll
            for (int s = 0; s < 4; ++s)
                afr[mt][s] = *(const bf8*)(Ct + (wm * 32 + mt * 16 + ln) * WPAD + s * 32 + quad * 8);
        #pragma unroll
        for (int t = 0; t < 4; ++t)
            #pragma unroll
            for (int s = 0; s < 4; ++s)
                bfr[t][s] = *(const bf8*)(Wb + (wn * 64 + t * 16 + ln) * WPAD + s * 32 + quad * 8);
        __syncthreads();   // frag reads done -> Ct, Wb free

        if (g < 2) {       // stage next W
            const bf8* Wn = (const bf8*)(WtT3 + (g + 1) * 16384);
            #pragma unroll
            for (int i = 0; i < 8; ++i) {
                int c = tid + i * 256;
                int n = c >> 4, k8 = c & 15;
                *(bf8*)(Wb + n * WPAD + k8 * 8) = Wn[c];
            }
        }

        f4 acc[2][4] = {};
        #pragma unroll
        for (int s = 0; s < 4; ++s)
            #pragma unroll
            for (int t = 0; t < 4; ++t) {
                acc[0][t] = __builtin_amdgcn_mfma_f32_16x16x32_bf16(afr[0][s], bfr[t][s], acc[0][t], 0, 0, 0);
                acc[1][t] = __builtin_amdgcn_mfma_f32_16x16x32_bf16(afr[1][s], bfr[t][s], acc[1][t], 0, 0, 0);
            }

        const float* bias = biases[g];
        #pragma unroll
        for (int mt = 0; mt < 2; ++mt)
            #pragma unroll
            for (int t = 0; t < 4; ++t) {
                int col = wn * 64 + t * 16 + ln;
                float bc = bias[col];
                #pragma unroll
                for (int r = 0; r < 4; ++r) {
                    int rloc = wm * 32 + mt * 16 + quad * 4 + r;
                    float vv = acc[mt][t][r] + bc;
                    if (g == 2) {
                        Out[(size_t)(row0 + rloc) * DD + col] = vv;
                    } else {
                        if (g == 1) vv = fmaxf(vv, 0.f);
                        Ct[rloc * WPAD + col] = f2bf(vv);
                    }
                }
            }
        __syncthreads();   // Ct rewritten + Wb(g+1) visible
    }
}

// ---------------------------------------------------------------------------
extern "C" void kernel_launch(void* const* d_in, const int* in_sizes, int n_in,
                              void* d_out, int out_size, void* d_ws, size_t ws_size,
                              hipStream_t stream)
{
    const float* vf   = (const float*)d_in[0];
    const int*   nbr  = (const int*)  d_in[1];
    const int*   vlen = (const int*)  d_in[2];
    const float* Wq   = (const float*)d_in[3];
    const float* bq   = (const float*)d_in[4];
    const float* Wk   = (const float*)d_in[5];
    const float* bk   = (const float*)d_in[6];
    const float* Wv   = (const float*)d_in[7];
    const float* bv   = (const float*)d_in[8];
    const float* Wo   = (const float*)d_in[9];
    const float* bo   = (const float*)d_in[10];
    const float* W1   = (const float*)d_in[11];
    const float* b1   = (const float*)d_in[12];
    const float* W2   = (const float*)d_in[13];
    const float* b2   = (const float*)d_in[14];

    float* out = (float*)d_out;

    const size_t SZ = (size_t)M_TOT * DD;
    unsigned short* WtT = (unsigned short*)d_ws;    // 6 x 16384 bf16
    unsigned short* qh  = WtT + 6 * 16384;
    unsigned short* kh  = qh + SZ;
    unsigned short* vh  = kh + SZ;

    cvt_wT<<<96, 256, 0, stream>>>(Wq, Wk, Wv, Wo, W1, W2, WtT);

    qkv_kernel<<<M_TOT / 64, 256, 0, stream>>>(vf, WtT, bq, bk, bv, qh, kh, vh);

    attn_ffn_kernel<<<M_TOT / 64, 256, 0, stream>>>(
        qh, kh, vh, nbr, vlen, WtT + 3 * 16384, bo, b1, b2, out);
}

// Round 5
// 132.717 us; speedup vs baseline: 1.3668x; 1.3668x over previous
//
#include <hip/hip_runtime.h>
#include <math.h>

#define BB 4
#define NN 8192
#define KNB 16
#define DD 128
#define SS 17            // K+1 (self + neighbors)
#define M_TOT (BB*NN)    // 32768
#define WPAD 136         // padded inner stride (elems) for LDS tiles

typedef __attribute__((ext_vector_type(8))) short          bf8;
typedef __attribute__((ext_vector_type(4))) float          f4;
typedef __attribute__((ext_vector_type(4))) unsigned short u16x4;

static __device__ __forceinline__ unsigned short f2bf(float f) {
    unsigned u = __builtin_bit_cast(unsigned, f);
    u += 0x7fffu + ((u >> 16) & 1u);        // round-to-nearest-even
    return (unsigned short)(u >> 16);
}
static __device__ __forceinline__ float bf2f(unsigned short h) {
    return __builtin_bit_cast(float, (unsigned)h << 16);
}
static __device__ __forceinline__ float bf2f_s(short h) {
    return __builtin_bit_cast(float, (unsigned)(unsigned short)h << 16);
}

// ---------------------------------------------------------------------------
// Transpose+convert the six 128x128 fp32 weights to bf16 W^T[n][k].
// ---------------------------------------------------------------------------
__global__ __launch_bounds__(256) void cvt_wT(
    const float* __restrict__ Wq, const float* __restrict__ Wk,
    const float* __restrict__ Wv, const float* __restrict__ Wo,
    const float* __restrict__ W1, const float* __restrict__ W2,
    unsigned short* __restrict__ out)
{
    int m = blockIdx.x >> 4;
    const float* src = (m == 0) ? Wq : (m == 1) ? Wk : (m == 2) ? Wv
                     : (m == 3) ? Wo : (m == 4) ? W1 : W2;
    unsigned short* dst = out + m * 16384;
    int o = (blockIdx.x & 15) * 1024 + threadIdx.x * 4;   // output idx [n][k]
    int n = o >> 7, k = o & 127;
    u16x4 r;
    #pragma unroll
    for (int i = 0; i < 4; ++i) r[i] = f2bf(src[(size_t)(k + i) * 128 + n]);
    *(u16x4*)(dst + o) = r;
}

// ---------------------------------------------------------------------------
// Fused fp32->bf16 convert + QKV projection. 64 rows/block, 4 waves.
// Wave tile 16 rows x 128 cols: afr (16 regs) persistent, bfr loaded per
// n-tile (16 regs live), acc 32 regs -> no spill pressure.
// Fragment maps (m89-verified): A[m=lane&15][k=quad*8+j],
// B[k=quad*8+j][n=lane&15], D[row=quad*4+r][col=lane&15].
// LDS 17.4 + 34.8 = 52.2 KB -> 3 blocks/CU.
// ---------------------------------------------------------------------------
__global__ __launch_bounds__(256) void qkv_kernel(
    const float* __restrict__ X, const unsigned short* __restrict__ WtT,
    const float* __restrict__ bq, const float* __restrict__ bk,
    const float* __restrict__ bv,
    unsigned short* __restrict__ qh, unsigned short* __restrict__ kh,
    unsigned short* __restrict__ vh)
{
    __shared__ unsigned short Xs[64 * WPAD];    // 17408 B
    __shared__ unsigned short Wb[128 * WPAD];   // 34816 B

    const int tid  = threadIdx.x;
    const int row0 = blockIdx.x * 64;

    // Stage X tile fp32 -> bf16 (coalesced float4 reads)
    {
        const float4* Xg = (const float4*)(X + (size_t)row0 * DD);
        #pragma unroll
        for (int i = 0; i < 8; ++i) {
            int idx = tid + i * 256;            // 0..2047
            int r = idx >> 5, c4 = idx & 31;
            float4 v = Xg[idx];
            u16x4 u;
            u[0] = f2bf(v.x); u[1] = f2bf(v.y); u[2] = f2bf(v.z); u[3] = f2bf(v.w);
            *(u16x4*)(Xs + r * WPAD + c4 * 4) = u;
        }
    }
    // Stage Wq^T
    #pragma unroll
    for (int i = 0; i < 8; ++i) {
        int c = tid + i * 256;
        int n = c >> 4, k8 = c & 15;
        *(bf8*)(Wb + n * WPAD + k8 * 8) = ((const bf8*)WtT)[c];
    }

    const int lane = tid & 63, wv = tid >> 6;   // wave owns rows wv*16..+15
    const int ln = lane & 15, quad = lane >> 4;
    __syncthreads();

    // A-frags: persistent across the 3 GEMMs (4 k-steps, 16 regs)
    bf8 afr[4];
    #pragma unroll
    for (int s = 0; s < 4; ++s)
        afr[s] = *(const bf8*)(Xs + (wv * 16 + ln) * WPAD + s * 32 + quad * 8);

    const float* biases[3] = { bq, bk, bv };
    unsigned short* outs[3] = { qh, kh, vh };

    #pragma unroll 1
    for (int g = 0; g < 3; ++g) {
        if (g > 0) {
            __syncthreads();   // all waves done reading Wb for g-1
            const bf8* Wn = (const bf8*)(WtT + g * 16384);
            #pragma unroll
            for (int i = 0; i < 8; ++i) {
                int c = tid + i * 256;
                int n = c >> 4, k8 = c & 15;
                *(bf8*)(Wb + n * WPAD + k8 * 8) = Wn[c];
            }
            __syncthreads();
        }

        f4 acc[8] = {};
        #pragma unroll
        for (int t = 0; t < 8; ++t) {
            bf8 bfr[4];
            #pragma unroll
            for (int s = 0; s < 4; ++s)
                bfr[s] = *(const bf8*)(Wb + (t * 16 + ln) * WPAD + s * 32 + quad * 8);
            #pragma unroll
            for (int s = 0; s < 4; ++s)
                acc[t] = __builtin_amdgcn_mfma_f32_16x16x32_bf16(afr[s], bfr[s], acc[t], 0, 0, 0);
        }

        const float* bias = biases[g];
        unsigned short* Y = outs[g];
        #pragma unroll
        for (int t = 0; t < 8; ++t) {
            int col = t * 16 + ln;
            float bc = bias[col];
            #pragma unroll
            for (int r = 0; r < 4; ++r) {
                int row = row0 + wv * 16 + quad * 4 + r;
                Y[(size_t)row * DD + col] = f2bf(acc[t][r] + bc);
            }
        }
    }
}

// ---------------------------------------------------------------------------
// Attention, register-resident. 16 lanes per vertex, lane owns 8 dims (16 B
// loads). Head = 4 lanes -> shfl_xor width 4. 16 vertices/block, 2048 blocks.
// XCD swizzle: batch b pinned to XCD pair {2b,2b+1} so each batch's 4 MB
// K+V slice stays resident in those XCDs' L2.
// ---------------------------------------------------------------------------
__global__ __launch_bounds__(256) void attn_kernel(
    const unsigned short* __restrict__ Qh, const unsigned short* __restrict__ Kh,
    const unsigned short* __restrict__ Vh, const int* __restrict__ nbr,
    const int* __restrict__ vlen, unsigned short* __restrict__ Ctx)
{
    const int tid  = threadIdx.x;
    const int vloc = tid >> 4;        // 0..15
    const int ln   = tid & 15;        // 8-dim slot
    const int blk  = blockIdx.x;
    const int b    = (blk & 7) >> 1;                 // batch from XCD pair
    const int j    = ((blk >> 3) << 1) | (blk & 1);  // within-batch group 0..511
    const int v    = b * NN + j * 16 + vloc;

    // q fragment: 8 dims
    bf8 q8 = *(const bf8*)(Qh + (size_t)v * DD + ln * 8);
    float qf[8];
    #pragma unroll
    for (int i = 0; i < 8; ++i) qf[i] = bf2f_s(q8[i]);

    int rows[SS];
    rows[0] = v;
    {
        const int4* np = (const int4*)(nbr + (size_t)v * KNB);
        #pragma unroll
        for (int i = 0; i < 4; ++i) {
            int4 n4 = np[i];
            rows[1 + i * 4 + 0] = b * NN + n4.x;
            rows[1 + i * 4 + 1] = b * NN + n4.y;
            rows[1 + i * 4 + 2] = b * NN + n4.z;
            rows[1 + i * 4 + 3] = b * NN + n4.w;
        }
    }

    // Pass 1: scores (lane's head = ln>>2)
    float sc[SS];
    #pragma unroll
    for (int s = 0; s < SS; ++s) {
        bf8 k8 = *(const bf8*)(Kh + (size_t)rows[s] * DD + ln * 8);
        float p = 0.f;
        #pragma unroll
        for (int i = 0; i < 8; ++i) p = fmaf(qf[i], bf2f_s(k8[i]), p);
        p += __shfl_xor(p, 1, 4);
        p += __shfl_xor(p, 2, 4);
        sc[s] = p * 0.17677669529663687f;   // 1/sqrt(32)
    }

    // Masked softmax over s in [0, len], redundantly per lane.
    const int len = vlen[v];
    float m = sc[0];
    #pragma unroll
    for (int s = 1; s < SS; ++s) m = (s <= len) ? fmaxf(m, sc[s]) : m;
    float sum = 0.f;
    #pragma unroll
    for (int s = 0; s < SS; ++s) {
        float e = (s <= len) ? __expf(sc[s] - m) : 0.f;
        sc[s] = e;
        sum += e;
    }
    const float inv = 1.f / sum;

    // Pass 2: weighted V accumulate
    float acc[8] = {};
    #pragma unroll
    for (int s = 0; s < SS; ++s) {
        bf8 v8 = *(const bf8*)(Vh + (size_t)rows[s] * DD + ln * 8);
        float w = sc[s] * inv;
        #pragma unroll
        for (int i = 0; i < 8; ++i) acc[i] = fmaf(w, bf2f_s(v8[i]), acc[i]);
    }
    bf8 r;
    #pragma unroll
    for (int i = 0; i < 8; ++i) r[i] = (short)f2bf(acc[i]);
    *(bf8*)(Ctx + (size_t)v * DD + ln * 8) = r;
}

// ---------------------------------------------------------------------------
// Fused Wo + FFN(W1,relu,W2): ctx -> out, chained through one LDS tile.
// 64 rows/block, 4 waves, wave tile 16x128. LDS 52.2 KB -> 3 blocks/CU.
// ---------------------------------------------------------------------------
__global__ __launch_bounds__(256) void ffn_kernel(
    const unsigned short* __restrict__ Ctxg, const unsigned short* __restrict__ WtT3,
    const float* __restrict__ bo, const float* __restrict__ b1,
    const float* __restrict__ b2, float* __restrict__ Out)
{
    __shared__ unsigned short Ct[64 * WPAD];
    __shared__ unsigned short Wb[128 * WPAD];

    const int tid  = threadIdx.x;
    const int row0 = blockIdx.x * 64;

    // Stage ctx tile (bf16, coalesced 16B) and Wo^T
    {
        const bf8* Cg = (const bf8*)(Ctxg + (size_t)row0 * DD);
        #pragma unroll
        for (int i = 0; i < 4; ++i) {
            int idx = tid + i * 256;            // 0..1023 chunks of 8 elems
            int r = idx >> 4, c8 = idx & 15;
            *(bf8*)(Ct + r * WPAD + c8 * 8) = Cg[idx];
        }
    }
    #pragma unroll
    for (int i = 0; i < 8; ++i) {
        int c = tid + i * 256;
        int n = c >> 4, k8 = c & 15;
        *(bf8*)(Wb + n * WPAD + k8 * 8) = ((const bf8*)WtT3)[c];
    }

    const int lane = tid & 63, wv = tid >> 6;
    const int ln = lane & 15, quad = lane >> 4;
    const float* biases[3] = { bo, b1, b2 };
    __syncthreads();

    #pragma unroll 1
    for (int g = 0; g < 3; ++g) {
        bf8 afr[4];
        #pragma unroll
        for (int s = 0; s < 4; ++s)
            afr[s] = *(const bf8*)(Ct + (wv * 16 + ln) * WPAD + s * 32 + quad * 8);

        f4 acc[8] = {};
        #pragma unroll
        for (int t = 0; t < 8; ++t) {
            bf8 bfr[4];
            #pragma unroll
            for (int s = 0; s < 4; ++s)
                bfr[s] = *(const bf8*)(Wb + (t * 16 + ln) * WPAD + s * 32 + quad * 8);
            #pragma unroll
            for (int s = 0; s < 4; ++s)
                acc[t] = __builtin_amdgcn_mfma_f32_16x16x32_bf16(afr[s], bfr[s], acc[t], 0, 0, 0);
        }

        __syncthreads();   // everyone done reading Ct & Wb

        const float* bias = biases[g];
        if (g == 2) {
            #pragma unroll
            for (int t = 0; t < 8; ++t) {
                int col = t * 16 + ln;
                float bc = bias[col];
                #pragma unroll
                for (int r = 0; r < 4; ++r) {
                    int row = row0 + wv * 16 + quad * 4 + r;
                    Out[(size_t)row * DD + col] = acc[t][r] + bc;
                }
            }
        } else {
            // stage next W while Ct is being rewritten
            const bf8* Wn = (const bf8*)(WtT3 + (g + 1) * 16384);
            #pragma unroll
            for (int i = 0; i < 8; ++i) {
                int c = tid + i * 256;
                int n = c >> 4, k8 = c & 15;
                *(bf8*)(Wb + n * WPAD + k8 * 8) = Wn[c];
            }
            #pragma unroll
            for (int t = 0; t < 8; ++t) {
                int col = t * 16 + ln;
                float bc = bias[col];
                #pragma unroll
                for (int r = 0; r < 4; ++r) {
                    int rloc = wv * 16 + quad * 4 + r;
                    float vv = acc[t][r] + bc;
                    if (g == 1) vv = fmaxf(vv, 0.f);
                    Ct[rloc * WPAD + col] = f2bf(vv);
                }
            }
            __syncthreads();   // new Ct + Wb visible before next g
        }
    }
}

// ---------------------------------------------------------------------------
extern "C" void kernel_launch(void* const* d_in, const int* in_sizes, int n_in,
                              void* d_out, int out_size, void* d_ws, size_t ws_size,
                              hipStream_t stream)
{
    const float* vf   = (const float*)d_in[0];
    const int*   nbr  = (const int*)  d_in[1];
    const int*   vlen = (const int*)  d_in[2];
    const float* Wq   = (const float*)d_in[3];
    const float* bq   = (const float*)d_in[4];
    const float* Wk   = (const float*)d_in[5];
    const float* bk   = (const float*)d_in[6];
    const float* Wv   = (const float*)d_in[7];
    const float* bv   = (const float*)d_in[8];
    const float* Wo   = (const float*)d_in[9];
    const float* bo   = (const float*)d_in[10];
    const float* W1   = (const float*)d_in[11];
    const float* b1   = (const float*)d_in[12];
    const float* W2   = (const float*)d_in[13];
    const float* b2   = (const float*)d_in[14];

    float* out = (float*)d_out;

    const size_t SZ = (size_t)M_TOT * DD;
    unsigned short* WtT = (unsigned short*)d_ws;    // 6 x 16384 bf16
    unsigned short* qh  = WtT + 6 * 16384;
    unsigned short* kh  = qh + SZ;
    unsigned short* vh  = kh + SZ;
    unsigned short* ctx = vh + SZ;

    cvt_wT<<<96, 256, 0, stream>>>(Wq, Wk, Wv, Wo, W1, W2, WtT);

    qkv_kernel<<<M_TOT / 64, 256, 0, stream>>>(vf, WtT, bq, bk, bv, qh, kh, vh);

    attn_kernel<<<M_TOT / 16, 256, 0, stream>>>(qh, kh, vh, nbr, vlen, ctx);

    ffn_kernel<<<M_TOT / 64, 256, 0, stream>>>(ctx, WtT + 3 * 16384, bo, b1, b2, out);
}